// Round 2
// baseline (627.621 us; speedup 1.0000x reference)
//
#include <hip/hip_runtime.h>

typedef unsigned short u16;
typedef unsigned int u32;
typedef __attribute__((ext_vector_type(8))) short short8;
typedef __attribute__((ext_vector_type(4))) float f32x4;

#define NN 20000
#define EE 640000

__device__ inline u16 f2bf(float f) {
    u32 x = __float_as_uint(f);
    return (u16)((x + 0x7FFFu + ((x >> 16) & 1u)) >> 16);
}
__device__ inline float lo16(u32 w) { return __uint_as_float(w << 16); }
__device__ inline float hi16(u32 w) { return __uint_as_float(w & 0xFFFF0000u); }
__device__ inline u32 packbf(float a, float b) { return ((u32)f2bf(b) << 16) | (u32)f2bf(a); }

// ---------------- zero ints ----------------
__global__ void zero_ints(int* p, int n) {
    int i = blockIdx.x * 256 + threadIdx.x;
    if (i < n) p[i] = 0;
}

// ---------------- weight prep: cast f32->bf16, transpose to [out][k] ----------------
// wt1[o][k]: k<1024 -> rgcn_weight[r=k/128][i=k%128][o] (flat k*128+o); k>=1024 -> root[(k-1024)*128+o]
// wt2[y][o][i] = W_y[i*128+o];  bcat[y*128+c] = b_y[c] (float)
__global__ void prep_weights(const float* rw, const float* root,
                             const float* Wq, const float* Wk, const float* Wv, const float* Ws,
                             const float* bq, const float* bk, const float* bv, const float* bs,
                             u16* wt1, u16* wt2, float* bcat) {
    int idx = blockIdx.x * 256 + threadIdx.x;
    const int S1 = 128 * 1152, S2 = 4 * 128 * 128;
    if (idx < S1) {
        int o = idx / 1152, k = idx - o * 1152;
        float v = (k < 1024) ? rw[k * 128 + o] : root[(k - 1024) * 128 + o];
        wt1[idx] = f2bf(v);
    } else if (idx < S1 + S2) {
        int j = idx - S1;
        int y = j >> 14, rem = j & 16383, o = rem >> 7, i = rem & 127;
        const float* W = (y == 0) ? Wq : (y == 1) ? Wk : (y == 2) ? Wv : Ws;
        wt2[j] = f2bf(W[i * 128 + o]);
    } else if (idx < S1 + S2 + 512) {
        int j = idx - (S1 + S2);
        int y = j >> 7, c = j & 127;
        const float* b = (y == 0) ? bq : (y == 1) ? bk : (y == 2) ? bv : bs;
        bcat[j] = b[c];
    }
}

// ---------------- CSR build ----------------
__global__ void count_kernel(const int* ei, const int* et, int* deg, int* cnt) {
    int e = blockIdx.x * 256 + threadIdx.x;
    if (e >= EE) return;
    int dst = ei[EE + e];
    int r = et[e];
    atomicAdd(&deg[dst], 1);
    atomicAdd(&cnt[dst * 8 + r], 1);
}

__global__ void scan_kernel(const int* deg, int* row_off, int n) {
    __shared__ int sums[1024];
    int t = threadIdx.x;
    const int CH = 20;
    int base = t * CH;
    int loc[CH];
    int s = 0;
    for (int i = 0; i < CH; i++) {
        int id = base + i;
        int d = (id < n) ? deg[id] : 0;
        s += d;
        loc[i] = s;
    }
    sums[t] = s;
    __syncthreads();
    for (int o = 1; o < 1024; o <<= 1) {
        int vadd = 0;
        if (t >= o) vadd = sums[t - o];
        __syncthreads();
        sums[t] += vadd;
        __syncthreads();
    }
    int excl = (t > 0) ? sums[t - 1] : 0;
    if (t == 0) row_off[0] = 0;
    for (int i = 0; i < CH; i++) {
        int id = base + i;
        if (id < n) row_off[id + 1] = excl + loc[i];
    }
}

__global__ void scatter_kernel(const int* ei, const int* et, const int* row_off,
                               int* fill, int* es, int* er) {
    int e = blockIdx.x * 256 + threadIdx.x;
    if (e >= EE) return;
    int dst = ei[EE + e];
    int src = ei[e];
    int r = et[e];
    int pos = row_off[dst] + atomicAdd(&fill[dst], 1);
    es[pos] = src;
    er[pos] = r;
}

// ---------------- RGCN pre-aggregation (input-space mean per relation) ----------------
// pre[n][r*128+d] = (1/max(cnt,1)) * sum_{e in in(n), rel=r} x[src][d];  pre[n][1024+d] = x[n][d]
__global__ __launch_bounds__(256) void rgcn_agg(const float* __restrict__ x,
                                                const int* __restrict__ row_off,
                                                const int* __restrict__ es,
                                                const int* __restrict__ er,
                                                const int* __restrict__ cnt,
                                                u16* __restrict__ pre) {
    int node = blockIdx.x * 4 + (threadIdx.x >> 6);
    int lane = threadIdx.x & 63;
    if (node >= NN) return;
    int p0 = row_off[node], p1 = row_off[node + 1];
    // copy x row into tail (fuses root projection into the big GEMM)
    float2 xv = *(const float2*)(x + (long)node * 128 + lane * 2);
    *(u32*)(pre + (long)node * 1152 + 1024 + lane * 2) = packbf(xv.x, xv.y);
    for (int r = 0; r < 8; r++) {
        int c = cnt[node * 8 + r];
        float inv = 1.0f / (float)(c > 1 ? c : 1);
        float a0 = 0.f, a1 = 0.f;
        for (int p = p0; p < p1; p++) {
            if (er[p] == r) {
                int s = es[p];
                float2 w = *(const float2*)(x + (long)s * 128 + lane * 2);
                a0 += w.x;
                a1 += w.y;
            }
        }
        *(u32*)(pre + (long)node * 1152 + r * 128 + lane * 2) = packbf(a0 * inv, a1 * inv);
    }
}

// ---------------- MFMA GEMM: C[rows x 128] = A[rows x K] * Bt^T + bias (opt relu) ----------------
// A row-major bf16 (lda elems), Bt = B transposed [128 out][K] bf16, bias float. C bf16.
__global__ __launch_bounds__(256) void gemm_kernel(const u16* __restrict__ A, int lda,
                                                   const u16* __restrict__ Bt, int ldbt,
                                                   const float* __restrict__ bias,
                                                   u16* __restrict__ C, int ldc,
                                                   int rows, int K, int relu,
                                                   long long yBt, long long yC, long long yBias) {
    Bt += blockIdx.y * yBt;
    C += blockIdx.y * yC;
    bias += blockIdx.y * yBias;
    __shared__ u16 As[64 * 136];   // stride 136 elems: keeps 16B alignment, max 2-way bank alias
    __shared__ u16 Bs[128 * 136];
    int tid = threadIdx.x;
    int w = tid >> 6;
    int lane = tid & 63;
    int quad = lane >> 4;
    int ml = lane & 15;
    int block_m = blockIdx.x * 64;

    f32x4 acc[8];
#pragma unroll
    for (int i = 0; i < 8; i++) acc[i] = (f32x4){0.f, 0.f, 0.f, 0.f};

    int rbase = tid >> 4;
    int cb = (tid & 15) * 8;

    for (int kb = 0; kb < K; kb += 128) {
        // stage A tile (64 x 128)
#pragma unroll
        for (int rep = 0; rep < 4; rep++) {
            int r = rbase + rep * 16;
            int gr = block_m + r;
            short8 val = {};
            if (gr < rows) val = *(const short8*)(A + (long)gr * lda + kb + cb);
            *(short8*)(As + r * 136 + cb) = val;
        }
        // stage Bt tile (128 x 128)
#pragma unroll
        for (int rep = 0; rep < 8; rep++) {
            int r = rbase + rep * 16;
            short8 val = *(const short8*)(Bt + (long)r * ldbt + kb + cb);
            *(short8*)(Bs + r * 136 + cb) = val;
        }
        __syncthreads();
#pragma unroll
        for (int ks = 0; ks < 4; ks++) {
            short8 af = *(const short8*)(As + (w * 16 + ml) * 136 + ks * 32 + quad * 8);
#pragma unroll
            for (int nt = 0; nt < 8; nt++) {
                short8 bfr = *(const short8*)(Bs + (nt * 16 + ml) * 136 + ks * 32 + quad * 8);
                acc[nt] = __builtin_amdgcn_mfma_f32_16x16x32_bf16(af, bfr, acc[nt], 0, 0, 0);
            }
        }
        __syncthreads();
    }
    // epilogue: D row = quad*4+i, col = ml (per 16x16 tile) [m89 layout]
#pragma unroll
    for (int nt = 0; nt < 8; nt++) {
        int col = nt * 16 + ml;
        float bv = bias[col];
#pragma unroll
        for (int i = 0; i < 4; i++) {
            int gr = block_m + w * 16 + quad * 4 + i;
            if (gr < rows) {
                float vv = acc[nt][i] + bv;
                if (relu) vv = fmaxf(vv, 0.f);
                C[(long)gr * ldc + col] = f2bf(vv);
            }
        }
    }
}

// ---------------- attention (online softmax per dst node, wave per node) + skip + relu ----------------
__global__ __launch_bounds__(256) void attn_kernel(const u16* __restrict__ q, const u16* __restrict__ k,
                                                   const u16* __restrict__ v, const u16* __restrict__ skip,
                                                   const int* __restrict__ row_off, const int* __restrict__ es,
                                                   float* __restrict__ out) {
    int node = blockIdx.x * 4 + (threadIdx.x >> 6);
    int lane = threadIdx.x & 63;
    if (node >= NN) return;
    int p0 = row_off[node], p1 = row_off[node + 1];
    u32 qw = *(const u32*)(q + (long)node * 128 + lane * 2);
    float q0 = lo16(qw), q1 = hi16(qw);
    float m = -INFINITY, l = 0.f, a0 = 0.f, a1 = 0.f;
    for (int p = p0; p < p1; p++) {
        int s = es[p];
        u32 kw = *(const u32*)(k + (long)s * 128 + lane * 2);
        float part = q0 * lo16(kw) + q1 * hi16(kw);
#pragma unroll
        for (int off = 1; off < 64; off <<= 1) part += __shfl_xor(part, off, 64);
        float sc = part * 0.08838834764831845f;  // 1/sqrt(128)
        float mn = fmaxf(m, sc);
        float scale = __expf(m - mn);  // m=-inf first iter -> 0
        float wgt = __expf(sc - mn);
        u32 vw = *(const u32*)(v + (long)s * 128 + lane * 2);
        l = l * scale + wgt;
        a0 = a0 * scale + wgt * lo16(vw);
        a1 = a1 * scale + wgt * hi16(vw);
        m = mn;
    }
    float r0 = (l > 0.f) ? a0 / l : 0.f;
    float r1 = (l > 0.f) ? a1 / l : 0.f;
    u32 sw = *(const u32*)(skip + (long)node * 128 + lane * 2);
    float2 o2;
    o2.x = fmaxf(r0 + lo16(sw), 0.f);
    o2.y = fmaxf(r1 + hi16(sw), 0.f);
    *(float2*)(out + (long)node * 128 + lane * 2) = o2;
}

extern "C" void kernel_launch(void* const* d_in, const int* in_sizes, int n_in,
                              void* d_out, int out_size, void* d_ws, size_t ws_size,
                              hipStream_t stream) {
    const float* x = (const float*)d_in[0];
    const int* ei = (const int*)d_in[1];
    const int* et = (const int*)d_in[2];
    const float* rw = (const float*)d_in[3];
    const float* root = (const float*)d_in[4];
    const float* rbias = (const float*)d_in[5];
    const float* Wq = (const float*)d_in[6];
    const float* bq = (const float*)d_in[7];
    const float* Wk = (const float*)d_in[8];
    const float* bk = (const float*)d_in[9];
    const float* Wv = (const float*)d_in[10];
    const float* bv = (const float*)d_in[11];
    const float* Ws = (const float*)d_in[12];
    const float* bs = (const float*)d_in[13];

    char* ws = (char*)d_ws;
    size_t off = 0;
    auto alloc = [&](size_t b) {
        size_t o = off;
        off = (off + b + 255) & ~(size_t)255;
        return o;
    };
    u16* pre = (u16*)(ws + alloc((size_t)NN * 1152 * 2));
    u16* h = (u16*)(ws + alloc((size_t)NN * 128 * 2));
    u16* qkvs = (u16*)(ws + alloc((size_t)4 * NN * 128 * 2));
    u16* wt1 = (u16*)(ws + alloc((size_t)128 * 1152 * 2));
    u16* wt2 = (u16*)(ws + alloc((size_t)4 * 128 * 128 * 2));
    float* bcat = (float*)(ws + alloc((size_t)512 * 4));
    int* deg = (int*)(ws + alloc((size_t)NN * 4));
    int* fill = (int*)(ws + alloc((size_t)NN * 4));
    int* cnt = (int*)(ws + alloc((size_t)NN * 8 * 4));
    int* row_off = (int*)(ws + alloc((size_t)(NN + 1) * 4));
    int* es = (int*)(ws + alloc((size_t)EE * 4));
    int* er = (int*)(ws + alloc((size_t)EE * 4));
    (void)ws_size;
    (void)in_sizes;
    (void)n_in;
    (void)out_size;

    // zero deg/fill/cnt (contiguous region incl. padding)
    int zn = (int)(((char*)cnt + (size_t)NN * 8 * 4 - (char*)deg) / 4);
    zero_ints<<<(zn + 255) / 256, 256, 0, stream>>>(deg, zn);

    prep_weights<<<(128 * 1152 + 4 * 128 * 128 + 512 + 255) / 256, 256, 0, stream>>>(
        rw, root, Wq, Wk, Wv, Ws, bq, bk, bv, bs, wt1, wt2, bcat);

    count_kernel<<<EE / 256, 256, 0, stream>>>(ei, et, deg, cnt);
    scan_kernel<<<1, 1024, 0, stream>>>(deg, row_off, NN);
    scatter_kernel<<<EE / 256, 256, 0, stream>>>(ei, et, row_off, fill, es, er);

    rgcn_agg<<<NN / 4, 256, 0, stream>>>(x, row_off, es, er, cnt, pre);

    // h = relu(pre @ [rgcn_weight; root] + rgcn_bias)   [N,1152]x[1152,128]
    gemm_kernel<<<dim3((NN + 63) / 64, 1), 256, 0, stream>>>(pre, 1152, wt1, 1152, rbias, h, 128,
                                                             NN, 1152, 1, 0, 0, 0);
    // q,k,v,skip = h @ {Wq,Wk,Wv,Ws} + {bq,bk,bv,bs}    [N,128]x[128,128] x4
    gemm_kernel<<<dim3((NN + 63) / 64, 4), 256, 0, stream>>>(h, 128, wt2, 128, bcat, qkvs, 128,
                                                             NN, 128, 0, (long long)128 * 128,
                                                             (long long)NN * 128, 128);

    attn_kernel<<<NN / 4, 256, 0, stream>>>(qkvs, qkvs + (size_t)NN * 128, qkvs + (size_t)2 * NN * 128,
                                            qkvs + (size_t)3 * NN * 128, row_off, es, (float*)d_out);
}

// Round 3
// 427.307 us; speedup vs baseline: 1.4688x; 1.4688x over previous
//
#include <hip/hip_runtime.h>

typedef unsigned short u16;
typedef unsigned int u32;
typedef __attribute__((ext_vector_type(8))) short short8;
typedef __attribute__((ext_vector_type(4))) float f32x4;

#define NN 20000
#define EE 640000

__device__ inline u16 f2bf(float f) {
    u32 x = __float_as_uint(f);
    return (u16)((x + 0x7FFFu + ((x >> 16) & 1u)) >> 16);
}
__device__ inline float lo16(u32 w) { return __uint_as_float(w << 16); }
__device__ inline float hi16(u32 w) { return __uint_as_float(w & 0xFFFF0000u); }
__device__ inline u32 packbf(float a, float b) { return ((u32)f2bf(b) << 16) | (u32)f2bf(a); }

// ---------------- zero ints ----------------
__global__ void zero_ints(int* p, int n) {
    int i = blockIdx.x * 256 + threadIdx.x;
    if (i < n) p[i] = 0;
}

// ---------------- weight prep: cast f32->bf16, transpose to [out][k] ----------------
__global__ void prep_weights(const float* rw, const float* root,
                             const float* Wq, const float* Wk, const float* Wv, const float* Ws,
                             const float* bq, const float* bk, const float* bv, const float* bs,
                             u16* wt1, u16* wt2, float* bcat) {
    int idx = blockIdx.x * 256 + threadIdx.x;
    const int S1 = 128 * 1152, S2 = 4 * 128 * 128;
    if (idx < S1) {
        int o = idx / 1152, k = idx - o * 1152;
        float v = (k < 1024) ? rw[k * 128 + o] : root[(k - 1024) * 128 + o];
        wt1[idx] = f2bf(v);
    } else if (idx < S1 + S2) {
        int j = idx - S1;
        int y = j >> 14, rem = j & 16383, o = rem >> 7, i = rem & 127;
        const float* W = (y == 0) ? Wq : (y == 1) ? Wk : (y == 2) ? Wv : Ws;
        wt2[j] = f2bf(W[i * 128 + o]);
    } else if (idx < S1 + S2 + 512) {
        int j = idx - (S1 + S2);
        int y = j >> 7, c = j & 127;
        const float* b = (y == 0) ? bq : (y == 1) ? bk : (y == 2) ? bv : bs;
        bcat[j] = b[c];
    }
}

// ---------------- CSR build (relation-sorted) ----------------
__global__ void count_kernel(const int* ei, const int* et, int* deg, int* cnt) {
    int e = blockIdx.x * 256 + threadIdx.x;
    if (e >= EE) return;
    int dst = ei[EE + e];
    int r = et[e];
    atomicAdd(&deg[dst], 1);
    atomicAdd(&cnt[dst * 8 + r], 1);
}

__global__ void scan_kernel(const int* deg, int* row_off, int n) {
    __shared__ int sums[1024];
    int t = threadIdx.x;
    const int CH = 20;
    int base = t * CH;
    int loc[CH];
    int s = 0;
    for (int i = 0; i < CH; i++) {
        int id = base + i;
        int d = (id < n) ? deg[id] : 0;
        s += d;
        loc[i] = s;
    }
    sums[t] = s;
    __syncthreads();
    for (int o = 1; o < 1024; o <<= 1) {
        int vadd = 0;
        if (t >= o) vadd = sums[t - o];
        __syncthreads();
        sums[t] += vadd;
        __syncthreads();
    }
    int excl = (t > 0) ? sums[t - 1] : 0;
    if (t == 0) row_off[0] = 0;
    for (int i = 0; i < CH; i++) {
        int id = base + i;
        if (id < n) row_off[id + 1] = excl + loc[i];
    }
}

// per-(node,rel) start offsets within the node's CSR segment
__global__ void sub_off_kernel(const int* row_off, const int* cnt, int* srt) {
    int n = blockIdx.x * 256 + threadIdx.x;
    if (n >= NN) return;
    int run = row_off[n];
#pragma unroll
    for (int r = 0; r < 8; r++) {
        srt[n * 8 + r] = run;
        run += cnt[n * 8 + r];
    }
}

__global__ void scatter_kernel(const int* ei, const int* et, const int* srt,
                               int* fill8, int* es) {
    int e = blockIdx.x * 256 + threadIdx.x;
    if (e >= EE) return;
    int dst = ei[EE + e];
    int src = ei[e];
    int r = et[e];
    int pos = srt[dst * 8 + r] + atomicAdd(&fill8[dst * 8 + r], 1);
    es[pos] = src;
}

// ---------------- RGCN pre-aggregation: single edge pass, relation-sorted ----------------
__global__ __launch_bounds__(256) void rgcn_agg(const float* __restrict__ x,
                                                const int* __restrict__ srt,
                                                const int* __restrict__ cnt,
                                                const int* __restrict__ es,
                                                u16* __restrict__ pre) {
    int node = blockIdx.x * 4 + (threadIdx.x >> 6);
    int lane = threadIdx.x & 63;
    if (node >= NN) return;
    // copy x row into tail (fuses root projection into the big GEMM)
    float2 xv = *(const float2*)(x + (long)node * 128 + lane * 2);
    *(u32*)(pre + (long)node * 1152 + 1024 + lane * 2) = packbf(xv.x, xv.y);
#pragma unroll 1
    for (int r = 0; r < 8; r++) {
        int c = cnt[node * 8 + r];
        int p0 = srt[node * 8 + r];
        float inv = 1.0f / (float)(c > 1 ? c : 1);
        float a0 = 0.f, a1 = 0.f;
        for (int i = 0; i < c; i++) {
            int s = __builtin_amdgcn_readfirstlane(es[p0 + i]);
            float2 w = *(const float2*)(x + (long)s * 128 + lane * 2);
            a0 += w.x;
            a1 += w.y;
        }
        *(u32*)(pre + (long)node * 1152 + r * 128 + lane * 2) = packbf(a0 * inv, a1 * inv);
    }
}

// ---------------- MFMA GEMM: C[rows x 128] = A[rows x K] * Bt^T + bias (opt relu) ----------------
__global__ __launch_bounds__(256) void gemm_kernel(const u16* __restrict__ A, int lda,
                                                   const u16* __restrict__ Bt, int ldbt,
                                                   const float* __restrict__ bias,
                                                   u16* __restrict__ C, int ldc,
                                                   int rows, int K, int relu,
                                                   long long yBt, long long yC, long long yBias) {
    Bt += blockIdx.y * yBt;
    C += blockIdx.y * yC;
    bias += blockIdx.y * yBias;
    __shared__ u16 As[64 * 136];
    __shared__ u16 Bs[128 * 136];
    int tid = threadIdx.x;
    int w = tid >> 6;
    int lane = tid & 63;
    int quad = lane >> 4;
    int ml = lane & 15;
    int block_m = blockIdx.x * 64;

    f32x4 acc[8];
#pragma unroll
    for (int i = 0; i < 8; i++) acc[i] = (f32x4){0.f, 0.f, 0.f, 0.f};

    int rbase = tid >> 4;
    int cb = (tid & 15) * 8;

    for (int kb = 0; kb < K; kb += 128) {
#pragma unroll
        for (int rep = 0; rep < 4; rep++) {
            int r = rbase + rep * 16;
            int gr = block_m + r;
            short8 val = {};
            if (gr < rows) val = *(const short8*)(A + (long)gr * lda + kb + cb);
            *(short8*)(As + r * 136 + cb) = val;
        }
#pragma unroll
        for (int rep = 0; rep < 8; rep++) {
            int r = rbase + rep * 16;
            short8 val = *(const short8*)(Bt + (long)r * ldbt + kb + cb);
            *(short8*)(Bs + r * 136 + cb) = val;
        }
        __syncthreads();
#pragma unroll
        for (int ks = 0; ks < 4; ks++) {
            short8 af = *(const short8*)(As + (w * 16 + ml) * 136 + ks * 32 + quad * 8);
#pragma unroll
            for (int nt = 0; nt < 8; nt++) {
                short8 bfr = *(const short8*)(Bs + (nt * 16 + ml) * 136 + ks * 32 + quad * 8);
                acc[nt] = __builtin_amdgcn_mfma_f32_16x16x32_bf16(af, bfr, acc[nt], 0, 0, 0);
            }
        }
        __syncthreads();
    }
#pragma unroll
    for (int nt = 0; nt < 8; nt++) {
        int col = nt * 16 + ml;
        float bv = bias[col];
#pragma unroll
        for (int i = 0; i < 4; i++) {
            int gr = block_m + w * 16 + quad * 4 + i;
            if (gr < rows) {
                float vv = acc[nt][i] + bv;
                if (relu) vv = fmaxf(vv, 0.f);
                C[(long)gr * ldc + col] = f2bf(vv);
            }
        }
    }
}

// ---------------- attention (online softmax per dst node, wave per node) + skip + relu ----------------
__global__ __launch_bounds__(256) void attn_kernel(const u16* __restrict__ q, const u16* __restrict__ k,
                                                   const u16* __restrict__ v, const u16* __restrict__ skip,
                                                   const int* __restrict__ row_off, const int* __restrict__ es,
                                                   float* __restrict__ out) {
    int node = blockIdx.x * 4 + (threadIdx.x >> 6);
    int lane = threadIdx.x & 63;
    if (node >= NN) return;
    int p0 = row_off[node], p1 = row_off[node + 1];
    u32 qw = *(const u32*)(q + (long)node * 128 + lane * 2);
    float q0 = lo16(qw), q1 = hi16(qw);
    float m = -INFINITY, l = 0.f, a0 = 0.f, a1 = 0.f;
    for (int p = p0; p < p1; p++) {
        int s = __builtin_amdgcn_readfirstlane(es[p]);
        u32 kw = *(const u32*)(k + (long)s * 128 + lane * 2);
        float part = q0 * lo16(kw) + q1 * hi16(kw);
#pragma unroll
        for (int off = 1; off < 64; off <<= 1) part += __shfl_xor(part, off, 64);
        float sc = part * 0.08838834764831845f;  // 1/sqrt(128)
        float mn = fmaxf(m, sc);
        float scale = __expf(m - mn);
        float wgt = __expf(sc - mn);
        u32 vw = *(const u32*)(v + (long)s * 128 + lane * 2);
        l = l * scale + wgt;
        a0 = a0 * scale + wgt * lo16(vw);
        a1 = a1 * scale + wgt * hi16(vw);
        m = mn;
    }
    float r0 = (l > 0.f) ? a0 / l : 0.f;
    float r1 = (l > 0.f) ? a1 / l : 0.f;
    u32 sw = *(const u32*)(skip + (long)node * 128 + lane * 2);
    float2 o2;
    o2.x = fmaxf(r0 + lo16(sw), 0.f);
    o2.y = fmaxf(r1 + hi16(sw), 0.f);
    *(float2*)(out + (long)node * 128 + lane * 2) = o2;
}

extern "C" void kernel_launch(void* const* d_in, const int* in_sizes, int n_in,
                              void* d_out, int out_size, void* d_ws, size_t ws_size,
                              hipStream_t stream) {
    const float* x = (const float*)d_in[0];
    const int* ei = (const int*)d_in[1];
    const int* et = (const int*)d_in[2];
    const float* rw = (const float*)d_in[3];
    const float* root = (const float*)d_in[4];
    const float* rbias = (const float*)d_in[5];
    const float* Wq = (const float*)d_in[6];
    const float* bq = (const float*)d_in[7];
    const float* Wk = (const float*)d_in[8];
    const float* bk = (const float*)d_in[9];
    const float* Wv = (const float*)d_in[10];
    const float* bv = (const float*)d_in[11];
    const float* Ws = (const float*)d_in[12];
    const float* bs = (const float*)d_in[13];

    char* ws = (char*)d_ws;
    size_t off = 0;
    auto alloc = [&](size_t b) {
        size_t o = off;
        off = (off + b + 255) & ~(size_t)255;
        return o;
    };
    u16* pre = (u16*)(ws + alloc((size_t)NN * 1152 * 2));
    u16* h = (u16*)(ws + alloc((size_t)NN * 128 * 2));
    u16* qkvs = (u16*)(ws + alloc((size_t)4 * NN * 128 * 2));
    u16* wt1 = (u16*)(ws + alloc((size_t)128 * 1152 * 2));
    u16* wt2 = (u16*)(ws + alloc((size_t)4 * 128 * 128 * 2));
    float* bcat = (float*)(ws + alloc((size_t)512 * 4));
    int* deg = (int*)(ws + alloc((size_t)NN * 4));          // |
    int* fill8 = (int*)(ws + alloc((size_t)NN * 8 * 4));    // | contiguous zero region
    int* cnt = (int*)(ws + alloc((size_t)NN * 8 * 4));      // |
    int* row_off = (int*)(ws + alloc((size_t)(NN + 1) * 4));
    int* srt = (int*)(ws + alloc((size_t)NN * 8 * 4));
    int* es = (int*)(ws + alloc((size_t)EE * 4));
    (void)ws_size;
    (void)in_sizes;
    (void)n_in;
    (void)out_size;

    int zn = (int)(((char*)cnt + (size_t)NN * 8 * 4 - (char*)deg) / 4);
    zero_ints<<<(zn + 255) / 256, 256, 0, stream>>>(deg, zn);

    prep_weights<<<(128 * 1152 + 4 * 128 * 128 + 512 + 255) / 256, 256, 0, stream>>>(
        rw, root, Wq, Wk, Wv, Ws, bq, bk, bv, bs, wt1, wt2, bcat);

    count_kernel<<<EE / 256, 256, 0, stream>>>(ei, et, deg, cnt);
    scan_kernel<<<1, 1024, 0, stream>>>(deg, row_off, NN);
    sub_off_kernel<<<(NN + 255) / 256, 256, 0, stream>>>(row_off, cnt, srt);
    scatter_kernel<<<EE / 256, 256, 0, stream>>>(ei, et, srt, fill8, es);

    rgcn_agg<<<NN / 4, 256, 0, stream>>>(x, srt, cnt, es, pre);

    gemm_kernel<<<dim3((NN + 63) / 64, 1), 256, 0, stream>>>(pre, 1152, wt1, 1152, rbias, h, 128,
                                                             NN, 1152, 1, 0, 0, 0);
    gemm_kernel<<<dim3((NN + 63) / 64, 4), 256, 0, stream>>>(h, 128, wt2, 128, bcat, qkvs, 128,
                                                             NN, 128, 0, (long long)128 * 128,
                                                             (long long)NN * 128, 128);

    attn_kernel<<<NN / 4, 256, 0, stream>>>(qkvs, qkvs + (size_t)NN * 128, qkvs + (size_t)2 * NN * 128,
                                            qkvs + (size_t)3 * NN * 128, row_off, es, (float*)d_out);
}

// Round 4
// 347.173 us; speedup vs baseline: 1.8078x; 1.2308x over previous
//
#include <hip/hip_runtime.h>

typedef unsigned short u16;
typedef unsigned int u32;
typedef __attribute__((ext_vector_type(8))) short short8;
typedef __attribute__((ext_vector_type(4))) float f32x4;

#define NN 20000
#define EE 640000

__device__ inline u16 f2bf(float f) {
    u32 x = __float_as_uint(f);
    return (u16)((x + 0x7FFFu + ((x >> 16) & 1u)) >> 16);
}
__device__ inline float lo16(u32 w) { return __uint_as_float(w << 16); }
__device__ inline float hi16(u32 w) { return __uint_as_float(w & 0xFFFF0000u); }
__device__ inline u32 packbf(float a, float b) { return ((u32)f2bf(b) << 16) | (u32)f2bf(a); }

// ---------------- zero ints ----------------
__global__ void zero_ints(int* p, int n) {
    int i = blockIdx.x * 256 + threadIdx.x;
    if (i < n) p[i] = 0;
}

// ---------------- weight prep: cast f32->bf16, transpose to [out][k] ----------------
__global__ void prep_weights(const float* rw, const float* root,
                             const float* Wq, const float* Wk, const float* Wv, const float* Ws,
                             const float* bq, const float* bk, const float* bv, const float* bs,
                             u16* wt1, u16* wt2, float* bcat) {
    int idx = blockIdx.x * 256 + threadIdx.x;
    const int S1 = 128 * 1152, S2 = 4 * 128 * 128;
    if (idx < S1) {
        int o = idx / 1152, k = idx - o * 1152;
        float v = (k < 1024) ? rw[k * 128 + o] : root[(k - 1024) * 128 + o];
        wt1[idx] = f2bf(v);
    } else if (idx < S1 + S2) {
        int j = idx - S1;
        int y = j >> 14, rem = j & 16383, o = rem >> 7, i = rem & 127;
        const float* W = (y == 0) ? Wq : (y == 1) ? Wk : (y == 2) ? Wv : Ws;
        wt2[j] = f2bf(W[i * 128 + o]);
    } else if (idx < S1 + S2 + 512) {
        int j = idx - (S1 + S2);
        int y = j >> 7, c = j & 127;
        const float* b = (y == 0) ? bq : (y == 1) ? bk : (y == 2) ? bv : bs;
        bcat[j] = b[c];
    }
}

// ---------------- CSR build (relation-sorted) ----------------
__global__ void count_kernel(const int* ei, const int* et, int* deg, int* cnt) {
    int e = blockIdx.x * 256 + threadIdx.x;
    if (e >= EE) return;
    int dst = ei[EE + e];
    int r = et[e];
    atomicAdd(&deg[dst], 1);
    atomicAdd(&cnt[dst * 8 + r], 1);
}

__global__ void scan_kernel(const int* deg, int* row_off, int n) {
    __shared__ int sums[1024];
    int t = threadIdx.x;
    const int CH = 20;
    int base = t * CH;
    int loc[CH];
    int s = 0;
    for (int i = 0; i < CH; i++) {
        int id = base + i;
        int d = (id < n) ? deg[id] : 0;
        s += d;
        loc[i] = s;
    }
    sums[t] = s;
    __syncthreads();
    for (int o = 1; o < 1024; o <<= 1) {
        int vadd = 0;
        if (t >= o) vadd = sums[t - o];
        __syncthreads();
        sums[t] += vadd;
        __syncthreads();
    }
    int excl = (t > 0) ? sums[t - 1] : 0;
    if (t == 0) row_off[0] = 0;
    for (int i = 0; i < CH; i++) {
        int id = base + i;
        if (id < n) row_off[id + 1] = excl + loc[i];
    }
}

// per-(node,rel) start offsets within the node's CSR segment
__global__ void sub_off_kernel(const int* row_off, const int* cnt, int* srt) {
    int n = blockIdx.x * 256 + threadIdx.x;
    if (n >= NN) return;
    int run = row_off[n];
#pragma unroll
    for (int r = 0; r < 8; r++) {
        srt[n * 8 + r] = run;
        run += cnt[n * 8 + r];
    }
}

__global__ void scatter_kernel(const int* ei, const int* et, const int* srt,
                               int* fill8, int* es) {
    int e = blockIdx.x * 256 + threadIdx.x;
    if (e >= EE) return;
    int dst = ei[EE + e];
    int src = ei[e];
    int r = et[e];
    int pos = srt[dst * 8 + r] + atomicAdd(&fill8[dst * 8 + r], 1);
    es[pos] = src;
}

// ---------------- RGCN pre-aggregation: half-wave per node, 4x edge ILP ----------------
__global__ __launch_bounds__(256) void rgcn_agg(const float* __restrict__ x,
                                                const int* __restrict__ srt,
                                                const int* __restrict__ cnt,
                                                const int* __restrict__ es,
                                                u16* __restrict__ pre) {
    int node = blockIdx.x * 8 + (threadIdx.x >> 5);
    int lane = threadIdx.x & 31;     // 4 dims/lane
    if (node >= NN) return;
    // copy x row into tail (fuses root projection into the big GEMM)
    float4 xv = *(const float4*)(x + (long)node * 128 + lane * 4);
    uint2 tw;
    tw.x = packbf(xv.x, xv.y);
    tw.y = packbf(xv.z, xv.w);
    *(uint2*)(pre + (long)node * 1152 + 1024 + lane * 4) = tw;
#pragma unroll 1
    for (int r = 0; r < 8; r++) {
        int c = cnt[node * 8 + r];
        int p0 = srt[node * 8 + r];
        float inv = 1.0f / (float)(c > 1 ? c : 1);
        float4 a = {0.f, 0.f, 0.f, 0.f};
        int i = 0;
        for (; i + 4 <= c; i += 4) {
            int s0 = es[p0 + i], s1 = es[p0 + i + 1], s2 = es[p0 + i + 2], s3 = es[p0 + i + 3];
            float4 w0 = *(const float4*)(x + (long)s0 * 128 + lane * 4);
            float4 w1 = *(const float4*)(x + (long)s1 * 128 + lane * 4);
            float4 w2 = *(const float4*)(x + (long)s2 * 128 + lane * 4);
            float4 w3 = *(const float4*)(x + (long)s3 * 128 + lane * 4);
            a.x += (w0.x + w1.x) + (w2.x + w3.x);
            a.y += (w0.y + w1.y) + (w2.y + w3.y);
            a.z += (w0.z + w1.z) + (w2.z + w3.z);
            a.w += (w0.w + w1.w) + (w2.w + w3.w);
        }
        for (; i < c; i++) {
            int s = es[p0 + i];
            float4 w = *(const float4*)(x + (long)s * 128 + lane * 4);
            a.x += w.x; a.y += w.y; a.z += w.z; a.w += w.w;
        }
        uint2 ow;
        ow.x = packbf(a.x * inv, a.y * inv);
        ow.y = packbf(a.z * inv, a.w * inv);
        *(uint2*)(pre + (long)node * 1152 + r * 128 + lane * 4) = ow;
    }
}

// ---------------- MFMA GEMM: C[rows x 128] = A[rows x K] * Bt^T + bias (opt relu) ----------------
__global__ __launch_bounds__(256) void gemm_kernel(const u16* __restrict__ A, int lda,
                                                   const u16* __restrict__ Bt, int ldbt,
                                                   const float* __restrict__ bias,
                                                   u16* __restrict__ C, int ldc,
                                                   int rows, int K, int relu,
                                                   long long yBt, long long yC, long long yBias) {
    Bt += blockIdx.y * yBt;
    C += blockIdx.y * yC;
    bias += blockIdx.y * yBias;
    __shared__ u16 As[64 * 136];
    __shared__ u16 Bs[128 * 136];
    int tid = threadIdx.x;
    int w = tid >> 6;
    int lane = tid & 63;
    int quad = lane >> 4;
    int ml = lane & 15;
    int block_m = blockIdx.x * 64;

    f32x4 acc[8];
#pragma unroll
    for (int i = 0; i < 8; i++) acc[i] = (f32x4){0.f, 0.f, 0.f, 0.f};

    int rbase = tid >> 4;
    int cb = (tid & 15) * 8;

    for (int kb = 0; kb < K; kb += 128) {
#pragma unroll
        for (int rep = 0; rep < 4; rep++) {
            int r = rbase + rep * 16;
            int gr = block_m + r;
            short8 val = {};
            if (gr < rows) val = *(const short8*)(A + (long)gr * lda + kb + cb);
            *(short8*)(As + r * 136 + cb) = val;
        }
#pragma unroll
        for (int rep = 0; rep < 8; rep++) {
            int r = rbase + rep * 16;
            short8 val = *(const short8*)(Bt + (long)r * ldbt + kb + cb);
            *(short8*)(Bs + r * 136 + cb) = val;
        }
        __syncthreads();
#pragma unroll
        for (int ks = 0; ks < 4; ks++) {
            short8 af = *(const short8*)(As + (w * 16 + ml) * 136 + ks * 32 + quad * 8);
#pragma unroll
            for (int nt = 0; nt < 8; nt++) {
                short8 bfr = *(const short8*)(Bs + (nt * 16 + ml) * 136 + ks * 32 + quad * 8);
                acc[nt] = __builtin_amdgcn_mfma_f32_16x16x32_bf16(af, bfr, acc[nt], 0, 0, 0);
            }
        }
        __syncthreads();
    }
#pragma unroll
    for (int nt = 0; nt < 8; nt++) {
        int col = nt * 16 + ml;
        float bv = bias[col];
#pragma unroll
        for (int i = 0; i < 4; i++) {
            int gr = block_m + w * 16 + quad * 4 + i;
            if (gr < rows) {
                float vv = acc[nt][i] + bv;
                if (relu) vv = fmaxf(vv, 0.f);
                C[(long)gr * ldc + col] = f2bf(vv);
            }
        }
    }
}

// ---------------- attention: half-wave per node, 4x edge ILP, online softmax ----------------
__global__ __launch_bounds__(256) void attn_kernel(const u16* __restrict__ q, const u16* __restrict__ k,
                                                   const u16* __restrict__ v, const u16* __restrict__ skip,
                                                   const int* __restrict__ row_off, const int* __restrict__ es,
                                                   float* __restrict__ out) {
    int node = blockIdx.x * 8 + (threadIdx.x >> 5);
    int lane = threadIdx.x & 31;     // 4 dims/lane
    if (node >= NN) return;
    int p0 = row_off[node], p1 = row_off[node + 1];
    uint2 qw = *(const uint2*)(q + (long)node * 128 + lane * 4);
    float q0 = lo16(qw.x), q1 = hi16(qw.x), q2 = lo16(qw.y), q3 = hi16(qw.y);
    const float SC = 0.08838834764831845f;  // 1/sqrt(128)
    float m = -INFINITY, l = 0.f;
    float4 a = {0.f, 0.f, 0.f, 0.f};
    int p = p0;
    for (; p + 4 <= p1; p += 4) {
        int s0 = es[p], s1 = es[p + 1], s2 = es[p + 2], s3 = es[p + 3];
        uint2 k0 = *(const uint2*)(k + (long)s0 * 128 + lane * 4);
        uint2 k1 = *(const uint2*)(k + (long)s1 * 128 + lane * 4);
        uint2 k2 = *(const uint2*)(k + (long)s2 * 128 + lane * 4);
        uint2 k3 = *(const uint2*)(k + (long)s3 * 128 + lane * 4);
        uint2 v0 = *(const uint2*)(v + (long)s0 * 128 + lane * 4);
        uint2 v1 = *(const uint2*)(v + (long)s1 * 128 + lane * 4);
        uint2 v2 = *(const uint2*)(v + (long)s2 * 128 + lane * 4);
        uint2 v3 = *(const uint2*)(v + (long)s3 * 128 + lane * 4);
        float t0 = q0 * lo16(k0.x) + q1 * hi16(k0.x) + q2 * lo16(k0.y) + q3 * hi16(k0.y);
        float t1 = q0 * lo16(k1.x) + q1 * hi16(k1.x) + q2 * lo16(k1.y) + q3 * hi16(k1.y);
        float t2 = q0 * lo16(k2.x) + q1 * hi16(k2.x) + q2 * lo16(k2.y) + q3 * hi16(k2.y);
        float t3 = q0 * lo16(k3.x) + q1 * hi16(k3.x) + q2 * lo16(k3.y) + q3 * hi16(k3.y);
#pragma unroll
        for (int off = 16; off >= 1; off >>= 1) {
            t0 += __shfl_xor(t0, off, 32);
            t1 += __shfl_xor(t1, off, 32);
            t2 += __shfl_xor(t2, off, 32);
            t3 += __shfl_xor(t3, off, 32);
        }
        t0 *= SC; t1 *= SC; t2 *= SC; t3 *= SC;
        float mx = fmaxf(fmaxf(t0, t1), fmaxf(t2, t3));
        float mn = fmaxf(m, mx);
        float scale = __expf(m - mn);
        float w0 = __expf(t0 - mn), w1 = __expf(t1 - mn), w2 = __expf(t2 - mn), w3 = __expf(t3 - mn);
        l = l * scale + ((w0 + w1) + (w2 + w3));
        a.x = a.x * scale + w0 * lo16(v0.x) + w1 * lo16(v1.x) + w2 * lo16(v2.x) + w3 * lo16(v3.x);
        a.y = a.y * scale + w0 * hi16(v0.x) + w1 * hi16(v1.x) + w2 * hi16(v2.x) + w3 * hi16(v3.x);
        a.z = a.z * scale + w0 * lo16(v0.y) + w1 * lo16(v1.y) + w2 * lo16(v2.y) + w3 * lo16(v3.y);
        a.w = a.w * scale + w0 * hi16(v0.y) + w1 * hi16(v1.y) + w2 * hi16(v2.y) + w3 * hi16(v3.y);
        m = mn;
    }
    for (; p < p1; p++) {
        int s = es[p];
        uint2 kw = *(const uint2*)(k + (long)s * 128 + lane * 4);
        uint2 vw = *(const uint2*)(v + (long)s * 128 + lane * 4);
        float t = q0 * lo16(kw.x) + q1 * hi16(kw.x) + q2 * lo16(kw.y) + q3 * hi16(kw.y);
#pragma unroll
        for (int off = 16; off >= 1; off >>= 1) t += __shfl_xor(t, off, 32);
        t *= SC;
        float mn = fmaxf(m, t);
        float scale = __expf(m - mn);
        float wgt = __expf(t - mn);
        l = l * scale + wgt;
        a.x = a.x * scale + wgt * lo16(vw.x);
        a.y = a.y * scale + wgt * hi16(vw.x);
        a.z = a.z * scale + wgt * lo16(vw.y);
        a.w = a.w * scale + wgt * hi16(vw.y);
        m = mn;
    }
    float invl = (l > 0.f) ? 1.0f / l : 0.f;
    uint2 sw = *(const uint2*)(skip + (long)node * 128 + lane * 4);
    float4 o4;
    o4.x = fmaxf(a.x * invl + lo16(sw.x), 0.f);
    o4.y = fmaxf(a.y * invl + hi16(sw.x), 0.f);
    o4.z = fmaxf(a.z * invl + lo16(sw.y), 0.f);
    o4.w = fmaxf(a.w * invl + hi16(sw.y), 0.f);
    *(float4*)(out + (long)node * 128 + lane * 4) = o4;
}

extern "C" void kernel_launch(void* const* d_in, const int* in_sizes, int n_in,
                              void* d_out, int out_size, void* d_ws, size_t ws_size,
                              hipStream_t stream) {
    const float* x = (const float*)d_in[0];
    const int* ei = (const int*)d_in[1];
    const int* et = (const int*)d_in[2];
    const float* rw = (const float*)d_in[3];
    const float* root = (const float*)d_in[4];
    const float* rbias = (const float*)d_in[5];
    const float* Wq = (const float*)d_in[6];
    const float* bq = (const float*)d_in[7];
    const float* Wk = (const float*)d_in[8];
    const float* bk = (const float*)d_in[9];
    const float* Wv = (const float*)d_in[10];
    const float* bv = (const float*)d_in[11];
    const float* Ws = (const float*)d_in[12];
    const float* bs = (const float*)d_in[13];

    char* ws = (char*)d_ws;
    size_t off = 0;
    auto alloc = [&](size_t b) {
        size_t o = off;
        off = (off + b + 255) & ~(size_t)255;
        return o;
    };
    u16* pre = (u16*)(ws + alloc((size_t)NN * 1152 * 2));
    u16* h = (u16*)(ws + alloc((size_t)NN * 128 * 2));
    u16* qkvs = (u16*)(ws + alloc((size_t)4 * NN * 128 * 2));
    u16* wt1 = (u16*)(ws + alloc((size_t)128 * 1152 * 2));
    u16* wt2 = (u16*)(ws + alloc((size_t)4 * 128 * 128 * 2));
    float* bcat = (float*)(ws + alloc((size_t)512 * 4));
    int* deg = (int*)(ws + alloc((size_t)NN * 4));          // |
    int* fill8 = (int*)(ws + alloc((size_t)NN * 8 * 4));    // | contiguous zero region
    int* cnt = (int*)(ws + alloc((size_t)NN * 8 * 4));      // |
    int* row_off = (int*)(ws + alloc((size_t)(NN + 1) * 4));
    int* srt = (int*)(ws + alloc((size_t)NN * 8 * 4));
    int* es = (int*)(ws + alloc((size_t)EE * 4));
    (void)ws_size;
    (void)in_sizes;
    (void)n_in;
    (void)out_size;

    int zn = (int)(((char*)cnt + (size_t)NN * 8 * 4 - (char*)deg) / 4);
    zero_ints<<<(zn + 255) / 256, 256, 0, stream>>>(deg, zn);

    prep_weights<<<(128 * 1152 + 4 * 128 * 128 + 512 + 255) / 256, 256, 0, stream>>>(
        rw, root, Wq, Wk, Wv, Ws, bq, bk, bv, bs, wt1, wt2, bcat);

    count_kernel<<<EE / 256, 256, 0, stream>>>(ei, et, deg, cnt);
    scan_kernel<<<1, 1024, 0, stream>>>(deg, row_off, NN);
    sub_off_kernel<<<(NN + 255) / 256, 256, 0, stream>>>(row_off, cnt, srt);
    scatter_kernel<<<EE / 256, 256, 0, stream>>>(ei, et, srt, fill8, es);

    rgcn_agg<<<(NN + 7) / 8, 256, 0, stream>>>(x, srt, cnt, es, pre);

    gemm_kernel<<<dim3((NN + 63) / 64, 1), 256, 0, stream>>>(pre, 1152, wt1, 1152, rbias, h, 128,
                                                             NN, 1152, 1, 0, 0, 0);
    gemm_kernel<<<dim3((NN + 63) / 64, 4), 256, 0, stream>>>(h, 128, wt2, 128, bcat, qkvs, 128,
                                                             NN, 128, 0, (long long)128 * 128,
                                                             (long long)NN * 128, 128);

    attn_kernel<<<(NN + 7) / 8, 256, 0, stream>>>(qkvs, qkvs + (size_t)NN * 128, qkvs + (size_t)2 * NN * 128,
                                                  qkvs + (size_t)3 * NN * 128, row_off, es, (float*)d_out);
}